// Round 1
// baseline (132.067 us; speedup 1.0000x reference)
//
#include <hip/hip_runtime.h>
#include <hip/hip_bf16.h>

#define B_   8
#define N_   128
#define H_   768
#define HID_ 384
#define L_   100

typedef float f32x4 __attribute__((ext_vector_type(4)));
typedef short s16x8 __attribute__((ext_vector_type(8)));

__device__ __forceinline__ short f2bf(float f) {
    __hip_bfloat16 h = __float2bfloat16(f);
    return __builtin_bit_cast(short, h);
}

// ---------------------------------------------------------------------------
// Prep: swizzle W1 (1536x384 fp32) into MFMA-B fragment layout, bf16.
// Layout: W1f[ct 0..47][kk 0..23][lane 0..63][e 0..7]
//   col c = ct*16 + (lane&15)   (c<384 -> W1_row col c ; else W1_col col c-384)
//   k     = kk*32 + (lane>>4)*8 + e
// ---------------------------------------------------------------------------
__global__ void prep_w1f(const float* __restrict__ W1, short* __restrict__ W1f) {
    int tid = blockIdx.x * 256 + threadIdx.x;
    if (tid >= 48 * 24 * 64) return;
    int lane = tid & 63;
    int kk   = (tid >> 6) % 24;
    int ct   = tid / (24 * 64);
    int c    = ct * 16 + (lane & 15);
    int k0   = kk * 32 + ((lane >> 4) << 3);
    short v[8];
#pragma unroll
    for (int e = 0; e < 8; ++e) {
        int k = k0 + e;
        float f = (c < HID_) ? W1[(size_t)k * HID_ + c]
                             : W1[(size_t)(H_ + k) * HID_ + (c - HID_)];
        v[e] = f2bf(f);
    }
    ((s16x8*)W1f)[tid] = *(const s16x8*)v;
}

// ---------------------------------------------------------------------------
// Prep: swizzle W2 (384x100 fp32) into MFMA-B fragment layout, bf16, L padded
// to 112.  Layout: W2f[kk 0..11][t 0..6][lane][e]
// ---------------------------------------------------------------------------
__global__ void prep_w2f(const float* __restrict__ W2, short* __restrict__ W2f) {
    int tid = blockIdx.x * 256 + threadIdx.x;
    if (tid >= 12 * 7 * 64) return;
    int lane = tid & 63;
    int t    = (tid >> 6) % 7;
    int kk   = tid / (7 * 64);
    int c    = t * 16 + (lane & 15);
    int k0   = kk * 32 + ((lane >> 4) << 3);
    short v[8];
#pragma unroll
    for (int e = 0; e < 8; ++e) {
        float f = (c < L_) ? W2[(size_t)(k0 + e) * L_ + c] : 0.0f;
        v[e] = f2bf(f);
    }
    ((s16x8*)W2f)[tid] = *(const s16x8*)v;
}

// ---------------------------------------------------------------------------
// P = repr @ W1_row + b1   (1024x384 fp32),   Q = repr @ W1_col (1024x384)
// 768 waves: wave = (row-tile rt 0..63) x (col-group cg 0..11, 64 cols each)
// ---------------------------------------------------------------------------
__global__ __launch_bounds__(256) void pq_gemm(
    const float* __restrict__ repr, const short* __restrict__ W1f,
    const float* __restrict__ b1,
    float* __restrict__ P, float* __restrict__ Q)
{
    const int wid  = blockIdx.x * 4 + (threadIdx.x >> 6);
    const int lane = threadIdx.x & 63;
    const int l15  = lane & 15;
    const int g    = lane >> 4;
    const int rt   = wid / 12;
    const int cg   = wid % 12;

    f32x4 acc[4];
#pragma unroll
    for (int n = 0; n < 4; ++n) { acc[n][0]=0.f; acc[n][1]=0.f; acc[n][2]=0.f; acc[n][3]=0.f; }

    const float* aptr  = repr + (size_t)(rt * 16 + l15) * H_ + (g << 3);
    const s16x8* bbase = (const s16x8*)W1f + (size_t)(cg * 4) * 24 * 64 + lane;

    for (int kk = 0; kk < 24; ++kk) {
        float a[8];
        *(float4*)&a[0] = *(const float4*)(aptr + kk * 32);
        *(float4*)&a[4] = *(const float4*)(aptr + kk * 32 + 4);
        s16x8 af;
#pragma unroll
        for (int e = 0; e < 8; ++e) af[e] = f2bf(a[e]);
#pragma unroll
        for (int n = 0; n < 4; ++n) {
            s16x8 bf = bbase[(size_t)(n * 24 + kk) * 64];
            acc[n] = __builtin_amdgcn_mfma_f32_16x16x32_bf16(af, bf, acc[n], 0, 0, 0);
        }
    }

    const int r0 = rt * 16 + (g << 2);
#pragma unroll
    for (int n = 0; n < 4; ++n) {
        int c = (cg * 4 + n) * 16 + l15;
#pragma unroll
        for (int r = 0; r < 4; ++r) {
            float v = acc[n][r];
            int row = r0 + r;
            if (c < HID_) P[(size_t)row * HID_ + c] = v + b1[c];
            else          Q[(size_t)row * HID_ + (c - HID_)] = v;
        }
    }
}

// ---------------------------------------------------------------------------
// Main fused kernel: out[b,i,j,l] = relu(P[b,j,:]+Q[b,i,:]) . W2 + b2
// Block = (b, 2 consecutive i).  Wave w owns j in [w*32, w*32+32).
// Each wave: 4 M-tiles (2 i x 2 j-tiles) x 7 L-tiles, K = 384 (12 steps).
// ---------------------------------------------------------------------------
__global__ __launch_bounds__(256, 2) void fused_out(
    const float* __restrict__ P, const float* __restrict__ Q,
    const short* __restrict__ W2f, const float* __restrict__ b2,
    float* __restrict__ out)
{
    const int blk  = blockIdx.x;
    const int b    = blk >> 6;
    const int i0   = (blk & 63) << 1;
    const int w    = threadIdx.x >> 6;
    const int lane = threadIdx.x & 63;
    const int l15  = lane & 15;
    const int g    = lane >> 4;
    const int j0   = w << 5;

    const float* __restrict__ Pb = P + (size_t)(b * N_) * HID_;
    const float* __restrict__ Q0 = Q + (size_t)(b * N_ + i0) * HID_;

    f32x4 acc[2][2][7];
#pragma unroll
    for (int ii = 0; ii < 2; ++ii)
#pragma unroll
        for (int jt = 0; jt < 2; ++jt)
#pragma unroll
            for (int t = 0; t < 7; ++t) {
                acc[ii][jt][t][0]=0.f; acc[ii][jt][t][1]=0.f;
                acc[ii][jt][t][2]=0.f; acc[ii][jt][t][3]=0.f;
            }

    const float* prow0 = Pb + (size_t)(j0 + l15) * HID_;
    const float* prow1 = Pb + (size_t)(j0 + 16 + l15) * HID_;

    for (int kk = 0; kk < 12; ++kk) {
        const int d0 = kk * 32 + (g << 3);

        float q0[8], q1[8], p0[8], p1[8];
        *(float4*)&q0[0] = *(const float4*)(Q0 + d0);
        *(float4*)&q0[4] = *(const float4*)(Q0 + d0 + 4);
        *(float4*)&q1[0] = *(const float4*)(Q0 + HID_ + d0);
        *(float4*)&q1[4] = *(const float4*)(Q0 + HID_ + d0 + 4);
        *(float4*)&p0[0] = *(const float4*)(prow0 + d0);
        *(float4*)&p0[4] = *(const float4*)(prow0 + d0 + 4);
        *(float4*)&p1[0] = *(const float4*)(prow1 + d0);
        *(float4*)&p1[4] = *(const float4*)(prow1 + d0 + 4);

        s16x8 af[2][2];
#pragma unroll
        for (int e = 0; e < 8; ++e) {
            af[0][0][e] = f2bf(fmaxf(p0[e] + q0[e], 0.f));
            af[0][1][e] = f2bf(fmaxf(p1[e] + q0[e], 0.f));
            af[1][0][e] = f2bf(fmaxf(p0[e] + q1[e], 0.f));
            af[1][1][e] = f2bf(fmaxf(p1[e] + q1[e], 0.f));
        }

        const s16x8* bfp = (const s16x8*)W2f + (size_t)(kk * 7) * 64 + lane;
#pragma unroll
        for (int t = 0; t < 7; ++t) {
            s16x8 bf = bfp[(size_t)t * 64];
#pragma unroll
            for (int ii = 0; ii < 2; ++ii)
#pragma unroll
                for (int jt = 0; jt < 2; ++jt)
                    acc[ii][jt][t] = __builtin_amdgcn_mfma_f32_16x16x32_bf16(
                        af[ii][jt], bf, acc[ii][jt][t], 0, 0, 0);
        }
    }

    float bias[7];
#pragma unroll
    for (int t = 0; t < 7; ++t) {
        int l = t * 16 + l15;
        bias[t] = (l < L_) ? b2[l] : 0.f;
    }

#pragma unroll
    for (int ii = 0; ii < 2; ++ii) {
        const size_t obase = (size_t)(b * N_ + (i0 + ii)) * N_ * L_;
#pragma unroll
        for (int jt = 0; jt < 2; ++jt) {
#pragma unroll
            for (int r = 0; r < 4; ++r) {
                int j = j0 + jt * 16 + (g << 2) + r;
                float* op = out + obase + (size_t)j * L_;
#pragma unroll
                for (int t = 0; t < 7; ++t) {
                    int l = t * 16 + l15;
                    if (l < L_) op[l] = acc[ii][jt][t][r] + bias[t];
                }
            }
        }
    }
}

// ---------------------------------------------------------------------------
extern "C" void kernel_launch(void* const* d_in, const int* in_sizes, int n_in,
                              void* d_out, int out_size, void* d_ws, size_t ws_size,
                              hipStream_t stream)
{
    const float* repr = (const float*)d_in[0];
    const float* W1   = (const float*)d_in[1];
    const float* b1   = (const float*)d_in[2];
    const float* W2   = (const float*)d_in[3];
    const float* b2   = (const float*)d_in[4];
    float* out = (float*)d_out;

    char* ws = (char*)d_ws;
    float* P   = (float*)(ws);                         // 1024*384*4 = 1572864 B
    float* Qm  = (float*)(ws + 1572864);               // 1572864 B
    short* W1f = (short*)(ws + 3145728);               // 48*24*64*8*2 = 1179648 B
    short* W2f = (short*)(ws + 3145728 + 1179648);     // 12*7*64*8*2 = 86016 B

    hipLaunchKernelGGL(prep_w1f, dim3(288), dim3(256), 0, stream, W1, W1f);
    hipLaunchKernelGGL(prep_w2f, dim3(21),  dim3(256), 0, stream, W2, W2f);
    hipLaunchKernelGGL(pq_gemm,  dim3(192), dim3(256), 0, stream, repr, W1f, b1, P, Qm);
    hipLaunchKernelGGL(fused_out, dim3(512), dim3(256), 0, stream, P, Qm, W2f, b2, out);
}